// Round 7
// baseline (1395.271 us; speedup 1.0000x reference)
//
#include <hip/hip_runtime.h>

#define N_NODES 50000
#define N_EDGES 600000
#define ODIM 40

typedef unsigned int u32;

// ---------------- adj layout detection (int64 vs int32) ----------------
__global__ void k_detect(const int* __restrict__ adj_w, int* __restrict__ mode) {
    if (threadIdx.x == 0 && blockIdx.x == 0) {
        int allz = 1;
        for (int i = 1; i < 128; i += 2)
            if (adj_w[i] != 0) { allz = 0; break; }
        *mode = allz;  // 1 => int64 layout
    }
}
__device__ __forceinline__ int adj_to(const int* a, int m, int e) {
    return m ? a[4 * e + 2] : a[2 * e + 1];
}
__device__ __forceinline__ int adj_fro(const int* a, int m, int e) {
    return m ? a[4 * e] : a[2 * e];
}

// ---------------- CSR build ----------------
__global__ void k_count(const int* __restrict__ adj_w, const int* __restrict__ mode,
                        int* __restrict__ deg) {
    int e = blockIdx.x * blockDim.x + threadIdx.x;
    if (e < N_EDGES) atomicAdd(&deg[adj_to(adj_w, *mode, e)], 1);
}

__global__ void k_scan(const int* __restrict__ deg, int* __restrict__ row_ptr,
                       int* __restrict__ cursor, float* __restrict__ inv_deg) {
    __shared__ int s[1024];
    __shared__ int carry_s;
    int tid = threadIdx.x;
    if (tid == 0) carry_s = 0;
    __syncthreads();
    for (int base = 0; base < N_NODES; base += 1024) {
        int i = base + tid;
        int v = (i < N_NODES) ? deg[i] : 0;
        s[tid] = v;
        __syncthreads();
        for (int off = 1; off < 1024; off <<= 1) {
            int t = (tid >= off) ? s[tid - off] : 0;
            __syncthreads();
            s[tid] += t;
            __syncthreads();
        }
        int c = carry_s;
        int excl = s[tid] - v;
        if (i < N_NODES) {
            row_ptr[i] = c + excl;
            cursor[i] = c + excl;
            inv_deg[i] = 1.0f / fmaxf((float)v, 1.0f);
        }
        int total = s[1023];
        __syncthreads();
        if (tid == 0) carry_s = c + total;
        __syncthreads();
    }
    if (tid == 0) row_ptr[N_NODES] = carry_s;
}

__global__ void k_fill(const int* __restrict__ adj_w, const int* __restrict__ mode,
                       int* __restrict__ cursor, int* __restrict__ edge_src) {
    int e = blockIdx.x * blockDim.x + threadIdx.x;
    if (e < N_EDGES) {
        int m = *mode;
        int to = adj_to(adj_w, m, e);
        int slot = atomicAdd(&cursor[to], 1);
        edge_src[slot] = adj_fro(adj_w, m, e);
    }
}

// ---- h = relu(X @ W_in + b_in); x broadcast via wave-uniform reads ----
__global__ __launch_bounds__(256) void k_ingemm(const float* __restrict__ X,
                                                const float* __restrict__ Wg,
                                                const float* __restrict__ bg,
                                                float* __restrict__ h) {
    __shared__ float2 Wp[128 * 64];
    int tid = threadIdx.x;
    for (int idx = tid; idx < 128 * 64; idx += 256) {
        int k = idx >> 6, l = idx & 63;
        Wp[idx] = make_float2(Wg[k * 128 + l], Wg[k * 128 + 64 + l]);
    }
    __syncthreads();
    int lane = tid & 63, wid = tid >> 6;
    float b0 = bg[lane], b1 = bg[64 + lane];
    for (int row = blockIdx.x * 4 + wid; row < N_NODES; row += gridDim.x * 4) {
        const float* xr = X + (size_t)row * 128;
        float a0 = b0, a1 = b1;
        for (int k = 0; k < 128; k++) {
            float xk = xr[k];
            float2 w = Wp[k * 64 + lane];
            a0 += xk * w.x;
            a1 += xk * w.y;
        }
        h[(size_t)row * 128 + lane] = fmaxf(a0, 0.f);
        h[(size_t)row * 128 + 64 + lane] = fmaxf(a1, 0.f);
    }
}

// partial = b + hin @ W_top (rows 0..127 of W_comb[l]); no relu
__global__ __launch_bounds__(256) void k_gemvA(const float* __restrict__ hin,
                                               float* __restrict__ pout,
                                               const float* __restrict__ Wg,
                                               const float* __restrict__ bg) {
    __shared__ float2 Wp[128 * 64];
    int tid = threadIdx.x;
    for (int idx = tid; idx < 128 * 64; idx += 256) {
        int k = idx >> 6, l = idx & 63;
        Wp[idx] = make_float2(Wg[k * 128 + l], Wg[k * 128 + 64 + l]);
    }
    __syncthreads();
    int lane = tid & 63, wid = tid >> 6;
    float b0 = bg[lane], b1 = bg[64 + lane];
    for (int row = blockIdx.x * 4 + wid; row < N_NODES; row += gridDim.x * 4) {
        const float* xr = hin + (size_t)row * 128;
        float a0 = b0, a1 = b1;
        for (int k = 0; k < 128; k++) {
            float xk = xr[k];
            float2 w = Wp[k * 64 + lane];
            a0 += xk * w.x;
            a1 += xk * w.y;
        }
        pout[(size_t)row * 128 + lane] = a0;
        pout[(size_t)row * 128 + 64 + lane] = a1;
    }
}

// hio[row] = relu(hio[row] + msg @ W_bot); msg staged through per-wave LDS
__global__ __launch_bounds__(256) void k_gemvB(const float* __restrict__ hin,
                                               float* __restrict__ hio,
                                               const float* __restrict__ Wg,
                                               const int* __restrict__ row_ptr,
                                               const int* __restrict__ edge_src,
                                               const float* __restrict__ inv_deg) {
    __shared__ float2 Wp[124 * 64];   // 63488B
    __shared__ float msgbuf[4][128];  // 2048B  (total exactly 64KB)
    int tid = threadIdx.x;
    for (int idx = tid; idx < 124 * 64; idx += 256) {
        int k = idx >> 6, l = idx & 63;
        Wp[idx] = make_float2(Wg[k * 128 + l], Wg[k * 128 + 64 + l]);
    }
    __syncthreads();
    int lane = tid & 63, wid = tid >> 6;
    const int NIT = (N_NODES + 2047) / 2048;  // grid fixed at 512 blocks
    for (int it = 0; it < NIT; it++) {
        int row = it * 2048 + blockIdx.x * 4 + wid;
        bool ok = row < N_NODES;
        float m0 = 0.f, m1 = 0.f;
        if (ok) {
            int e0 = row_ptr[row], e1 = row_ptr[row + 1];
            for (int e = e0; e < e1; e++) {
                const float* hs = hin + (size_t)edge_src[e] * 128;
                m0 += hs[lane];
                m1 += hs[64 + lane];
            }
            float inv = inv_deg[row];
            m0 *= inv;
            m1 *= inv;
        }
        msgbuf[wid][lane] = m0;
        msgbuf[wid][64 + lane] = m1;
        __syncthreads();
        float a0 = 0.f, a1 = 0.f;
        if (ok) {
            a0 = hio[(size_t)row * 128 + lane];
            a1 = hio[(size_t)row * 128 + 64 + lane];
        }
        for (int k = 0; k < 124; k++) {
            float xk = msgbuf[wid][k];
            float2 w = Wp[k * 64 + lane];
            a0 += xk * w.x;
            a1 += xk * w.y;
        }
        for (int k = 124; k < 128; k++) {
            float xk = msgbuf[wid][k];
            a0 += xk * Wg[k * 128 + lane];
            a1 += xk * Wg[k * 128 + 64 + lane];
        }
        if (ok) {
            hio[(size_t)row * 128 + lane] = fmaxf(a0, 0.f);
            hio[(size_t)row * 128 + 64 + lane] = fmaxf(a1, 0.f);
        }
        __syncthreads();
    }
}

// out = h @ W_out + b_out — FLOAT32 output (reference returns f32)
__global__ __launch_bounds__(256) void k_outgemm(const float* __restrict__ hin,
                                                 const float* __restrict__ Wg,
                                                 const float* __restrict__ bg,
                                                 float* __restrict__ out) {
    __shared__ float Wl[128 * 64];  // cols padded 40->64 with zeros
    int tid = threadIdx.x;
    for (int idx = tid; idx < 128 * 64; idx += 256) {
        int k = idx >> 6, c = idx & 63;
        Wl[idx] = (c < ODIM) ? Wg[k * ODIM + c] : 0.f;
    }
    __syncthreads();
    int lane = tid & 63, wid = tid >> 6;
    float b = (lane < ODIM) ? bg[lane] : 0.f;
    for (int row = blockIdx.x * 4 + wid; row < N_NODES; row += gridDim.x * 4) {
        const float* xr = hin + (size_t)row * 128;
        float a = b;
        for (int k = 0; k < 128; k++) {
            a += xr[k] * Wl[k * 64 + lane];
        }
        if (lane < ODIM) out[(size_t)row * ODIM + lane] = a;
    }
}

extern "C" void kernel_launch(void* const* d_in, const int* in_sizes, int n_in,
                              void* d_out, int out_size, void* d_ws, size_t ws_size,
                              hipStream_t stream) {
    // size-keyed input resolution with positional fallback (dict order)
    int ix[8] = {0, 1, 2, 3, 4, 5, 6, 7};
    int tmp[8] = {-1, -1, -1, -1, -1, -1, -1, -1};
    for (int i = 0; i < n_in && i < 8; i++) {
        switch (in_sizes[i]) {
            case 6400000: tmp[0] = i; break;                  // nodes_feats
            case 1200000: case 2400000: tmp[1] = i; break;    // adj_list
            case 16384:   tmp[2] = i; break;                  // W_in
            case 128:     tmp[3] = i; break;                  // b_in
            case 65536:   tmp[4] = i; break;                  // W_comb
            case 256:     tmp[5] = i; break;                  // b_comb
            case 5120:    tmp[6] = i; break;                  // W_out
            case 40:      tmp[7] = i; break;                  // b_out
        }
    }
    int found = 0;
    for (int j = 0; j < 8; j++) found += (tmp[j] >= 0);
    if (found == 8) for (int j = 0; j < 8; j++) ix[j] = tmp[j];

    const float* X      = (const float*)d_in[ix[0]];
    const int*   adj_w  = (const int*)d_in[ix[1]];
    const float* W_in   = (const float*)d_in[ix[2]];
    const float* b_in   = (const float*)d_in[ix[3]];
    const float* W_comb = (const float*)d_in[ix[4]];
    const float* b_comb = (const float*)d_in[ix[5]];
    const float* W_out  = (const float*)d_in[ix[6]];
    const float* b_out  = (const float*)d_in[ix[7]];
    float* out = (float*)d_out;

    // ws layout: CSR block first (3.2MB), then h/hn f32 (51.2MB); proven to fit
    char* base = (char*)d_ws;
    int*   deg      = (int*)(base + 0);
    int*   row_ptr  = (int*)(base + 200000);
    int*   cursor   = (int*)(base + 400004);
    float* inv_deg  = (float*)(base + 600004);
    int*   mode     = (int*)(base + 800004);
    int*   edge_src = (int*)(base + 800008);
    float* h        = (float*)(base + 3200016);
    float* hn       = h + 6400000;

    hipMemsetAsync(deg, 0, N_NODES * sizeof(int), stream);
    k_detect<<<1, 64, 0, stream>>>(adj_w, mode);
    k_count<<<(N_EDGES + 255) / 256, 256, 0, stream>>>(adj_w, mode, deg);
    k_scan<<<1, 1024, 0, stream>>>(deg, row_ptr, cursor, inv_deg);
    k_fill<<<(N_EDGES + 255) / 256, 256, 0, stream>>>(adj_w, mode, cursor, edge_src);

    const float* W0t = W_comb;                 // layer 0 rows 0..127
    const float* W0b = W_comb + 128 * 128;     // layer 0 rows 128..255
    const float* W1t = W_comb + 32768;         // layer 1 rows 0..127
    const float* W1b = W_comb + 32768 + 128 * 128;

    k_ingemm<<<512, 256, 0, stream>>>(X, W_in, b_in, h);
    k_gemvA<<<512, 256, 0, stream>>>(h, hn, W0t, b_comb);
    k_gemvB<<<512, 256, 0, stream>>>(h, hn, W0b, row_ptr, edge_src, inv_deg);
    k_gemvA<<<512, 256, 0, stream>>>(hn, h, W1t, b_comb + 128);
    k_gemvB<<<512, 256, 0, stream>>>(hn, h, W1b, row_ptr, edge_src, inv_deg);
    k_outgemm<<<512, 256, 0, stream>>>(h, W_out, b_out, out);
}

// Round 8
// 625.685 us; speedup vs baseline: 2.2300x; 2.2300x over previous
//
#include <hip/hip_runtime.h>

#define N_NODES 50000
#define N_EDGES 600000

// ---------------- adj layout detection (int64 vs int32) ----------------
__global__ void k_detect(const int* __restrict__ adj_w, int* __restrict__ mode) {
    if (threadIdx.x == 0 && blockIdx.x == 0) {
        int allz = 1;
        for (int i = 1; i < 128; i += 2)
            if (adj_w[i] != 0) { allz = 0; break; }
        *mode = allz;  // 1 => int64 layout
    }
}
__device__ __forceinline__ int adj_to(const int* a, int m, int e) {
    return m ? a[4 * e + 2] : a[2 * e + 1];
}
__device__ __forceinline__ int adj_fro(const int* a, int m, int e) {
    return m ? a[4 * e] : a[2 * e];
}

// ---------------- CSR build ----------------
__global__ void k_count(const int* __restrict__ adj_w, const int* __restrict__ mode,
                        int* __restrict__ deg) {
    int e = blockIdx.x * blockDim.x + threadIdx.x;
    if (e < N_EDGES) atomicAdd(&deg[adj_to(adj_w, *mode, e)], 1);
}

__global__ void k_scan(const int* __restrict__ deg, int* __restrict__ row_ptr,
                       int* __restrict__ cursor, float* __restrict__ inv_deg) {
    __shared__ int s[1024];
    __shared__ int carry_s;
    int tid = threadIdx.x;
    if (tid == 0) carry_s = 0;
    __syncthreads();
    for (int base = 0; base < N_NODES; base += 1024) {
        int i = base + tid;
        int v = (i < N_NODES) ? deg[i] : 0;
        s[tid] = v;
        __syncthreads();
        for (int off = 1; off < 1024; off <<= 1) {
            int t = (tid >= off) ? s[tid - off] : 0;
            __syncthreads();
            s[tid] += t;
            __syncthreads();
        }
        int c = carry_s;
        int excl = s[tid] - v;
        if (i < N_NODES) {
            row_ptr[i] = c + excl;
            cursor[i] = c + excl;
            inv_deg[i] = 1.0f / fmaxf((float)v, 1.0f);
        }
        int total = s[1023];
        __syncthreads();
        if (tid == 0) carry_s = c + total;
        __syncthreads();
    }
    if (tid == 0) row_ptr[N_NODES] = carry_s;
}

__global__ void k_fill(const int* __restrict__ adj_w, const int* __restrict__ mode,
                       int* __restrict__ cursor, int* __restrict__ edge_src) {
    int e = blockIdx.x * blockDim.x + threadIdx.x;
    if (e < N_EDGES) {
        int m = *mode;
        int to = adj_to(adj_w, m, e);
        int slot = atomicAdd(&cursor[to], 1);
        edge_src[slot] = adj_fro(adj_w, m, e);
    }
}

// ---- dense GEMM out[row] = [relu](bias + in[row] @ W), W (128x128) in registers ----
// 256 thr: wave w=t>>6, lane l. col c = w*32+(l&31); k-half q = l>>5.
// Each thread: 64 W regs. 8-row LDS tile (4KB) -> high occupancy.
template <bool RELU>
__global__ __launch_bounds__(256) void k_dense(const float* __restrict__ in,
                                               float* __restrict__ outp,
                                               const float* __restrict__ W,
                                               const float* __restrict__ bias) {
    __shared__ __align__(16) float xs[8][128];
    const int t = threadIdx.x, w = t >> 6, l = t & 63;
    const int q = l >> 5, c = w * 32 + (l & 31);
    float wr[64];
#pragma unroll
    for (int j = 0; j < 64; j++) wr[j] = W[(64 * q + j) * 128 + c];
    const float b = bias[c];
    const int nch = N_NODES / 8;  // 6250, exact
    for (int ch = blockIdx.x; ch < nch; ch += gridDim.x) {
        const int R0 = ch * 8;
        ((float4*)xs)[t] = ((const float4*)(in + (size_t)R0 * 128))[t];
        __syncthreads();
#pragma unroll
        for (int r = 0; r < 8; r++) {
            float a = 0.f;
#pragma unroll
            for (int jj = 0; jj < 16; jj++) {
                float4 x4 = *(const float4*)&xs[r][64 * q + jj * 4];
                a += x4.x * wr[jj * 4] + x4.y * wr[jj * 4 + 1] +
                     x4.z * wr[jj * 4 + 2] + x4.w * wr[jj * 4 + 3];
            }
            a += __shfl_xor(a, 32);
            if (l < 32) {
                const size_t o = (size_t)(R0 + r) * 128 + c;
                float v = a + b;
                if (RELU) v = fmaxf(v, 0.f);
                outp[o] = v;
            }
        }
        __syncthreads();
    }
}

// ---- fused gather + dense: hio[row] = relu(hio[row] + msg[row] @ W) ----
// Phase 1: wave w gathers msg rows R0+2w, R0+2w+1 into LDS (float2/lane, coalesced).
// Phase 2: same register-W dense structure as k_dense.
__global__ __launch_bounds__(256) void k_msggemm(const float* __restrict__ hin,
                                                 float* __restrict__ hio,
                                                 const float* __restrict__ W,
                                                 const int* __restrict__ row_ptr,
                                                 const int* __restrict__ edge_src,
                                                 const float* __restrict__ inv_deg) {
    __shared__ __align__(16) float xs[8][128];
    const int t = threadIdx.x, w = t >> 6, l = t & 63;
    const int q = l >> 5, c = w * 32 + (l & 31);
    float wr[64];
#pragma unroll
    for (int j = 0; j < 64; j++) wr[j] = W[(64 * q + j) * 128 + c];
    const float2* h2 = (const float2*)hin;
    const int nch = N_NODES / 8;
    for (int ch = blockIdx.x; ch < nch; ch += gridDim.x) {
        const int R0 = ch * 8;
        for (int rr = 0; rr < 2; rr++) {
            const int row = R0 + 2 * w + rr;
            const int e0 = row_ptr[row], e1 = row_ptr[row + 1];
            float ax = 0.f, ay = 0.f, bx = 0.f, by = 0.f;
            int e = e0;
            for (; e + 1 < e1; e += 2) {
                const int s0 = edge_src[e], s1 = edge_src[e + 1];
                float2 v0 = h2[(size_t)s0 * 64 + l];
                float2 v1 = h2[(size_t)s1 * 64 + l];
                ax += v0.x; ay += v0.y; bx += v1.x; by += v1.y;
            }
            if (e < e1) {
                float2 v = h2[(size_t)edge_src[e] * 64 + l];
                ax += v.x; ay += v.y;
            }
            const float inv = inv_deg[row];
            float2 m;
            m.x = (ax + bx) * inv;
            m.y = (ay + by) * inv;
            *(float2*)&xs[2 * w + rr][2 * l] = m;
        }
        __syncthreads();
#pragma unroll
        for (int r = 0; r < 8; r++) {
            float a = 0.f;
#pragma unroll
            for (int jj = 0; jj < 16; jj++) {
                float4 x4 = *(const float4*)&xs[r][64 * q + jj * 4];
                a += x4.x * wr[jj * 4] + x4.y * wr[jj * 4 + 1] +
                     x4.z * wr[jj * 4 + 2] + x4.w * wr[jj * 4 + 3];
            }
            a += __shfl_xor(a, 32);
            if (l < 32) {
                const size_t o = (size_t)(R0 + r) * 128 + c;
                hio[o] = fmaxf(a + hio[o], 0.f);
            }
        }
        __syncthreads();
    }
}

// ---- out = h @ W_out + b_out (f32 out). c = w*16+(l&15) (pad 40->64), q = l>>4. ----
__global__ __launch_bounds__(256) void k_outv2(const float* __restrict__ hin,
                                               const float* __restrict__ W,
                                               const float* __restrict__ bias,
                                               float* __restrict__ outp) {
    __shared__ __align__(16) float xs[8][128];
    const int t = threadIdx.x, w = t >> 6, l = t & 63;
    const int q = l >> 4, c = w * 16 + (l & 15);
    float wr[32];
#pragma unroll
    for (int j = 0; j < 32; j++) wr[j] = (c < 40) ? W[(32 * q + j) * 40 + c] : 0.f;
    const float b = (c < 40) ? bias[c] : 0.f;
    const int nch = N_NODES / 8;
    for (int ch = blockIdx.x; ch < nch; ch += gridDim.x) {
        const int R0 = ch * 8;
        ((float4*)xs)[t] = ((const float4*)(hin + (size_t)R0 * 128))[t];
        __syncthreads();
#pragma unroll
        for (int r = 0; r < 8; r++) {
            float a = 0.f;
#pragma unroll
            for (int jj = 0; jj < 8; jj++) {
                float4 x4 = *(const float4*)&xs[r][32 * q + jj * 4];
                a += x4.x * wr[jj * 4] + x4.y * wr[jj * 4 + 1] +
                     x4.z * wr[jj * 4 + 2] + x4.w * wr[jj * 4 + 3];
            }
            a += __shfl_xor(a, 16);
            a += __shfl_xor(a, 32);
            if (l < 16 && c < 40) outp[(size_t)(R0 + r) * 40 + c] = a + b;
        }
        __syncthreads();
    }
}

extern "C" void kernel_launch(void* const* d_in, const int* in_sizes, int n_in,
                              void* d_out, int out_size, void* d_ws, size_t ws_size,
                              hipStream_t stream) {
    // size-keyed input resolution with positional fallback (dict order)
    int ix[8] = {0, 1, 2, 3, 4, 5, 6, 7};
    int tmp[8] = {-1, -1, -1, -1, -1, -1, -1, -1};
    for (int i = 0; i < n_in && i < 8; i++) {
        switch (in_sizes[i]) {
            case 6400000: tmp[0] = i; break;
            case 1200000: case 2400000: tmp[1] = i; break;
            case 16384:   tmp[2] = i; break;
            case 128:     tmp[3] = i; break;
            case 65536:   tmp[4] = i; break;
            case 256:     tmp[5] = i; break;
            case 5120:    tmp[6] = i; break;
            case 40:      tmp[7] = i; break;
        }
    }
    int found = 0;
    for (int j = 0; j < 8; j++) found += (tmp[j] >= 0);
    if (found == 8) for (int j = 0; j < 8; j++) ix[j] = tmp[j];

    const float* X      = (const float*)d_in[ix[0]];
    const int*   adj_w  = (const int*)d_in[ix[1]];
    const float* W_in   = (const float*)d_in[ix[2]];
    const float* b_in   = (const float*)d_in[ix[3]];
    const float* W_comb = (const float*)d_in[ix[4]];
    const float* b_comb = (const float*)d_in[ix[5]];
    const float* W_out  = (const float*)d_in[ix[6]];
    const float* b_out  = (const float*)d_in[ix[7]];
    float* out = (float*)d_out;

    // ws layout: CSR block (3.2MB) + h/hn f32 (51.2MB) — proven to fit
    char* base = (char*)d_ws;
    int*   deg      = (int*)(base + 0);
    int*   row_ptr  = (int*)(base + 200000);
    int*   cursor   = (int*)(base + 400004);
    float* inv_deg  = (float*)(base + 600004);
    int*   mode     = (int*)(base + 800004);
    int*   edge_src = (int*)(base + 800008);
    float* h        = (float*)(base + 3200016);
    float* hn       = h + 6400000;

    hipMemsetAsync(deg, 0, N_NODES * sizeof(int), stream);
    k_detect<<<1, 64, 0, stream>>>(adj_w, mode);
    k_count<<<(N_EDGES + 255) / 256, 256, 0, stream>>>(adj_w, mode, deg);
    k_scan<<<1, 1024, 0, stream>>>(deg, row_ptr, cursor, inv_deg);
    k_fill<<<(N_EDGES + 255) / 256, 256, 0, stream>>>(adj_w, mode, cursor, edge_src);

    const float* W0t = W_comb;                  // layer 0 rows 0..127  (h part)
    const float* W0b = W_comb + 16384;          // layer 0 rows 128..255 (msg part)
    const float* W1t = W_comb + 32768;          // layer 1
    const float* W1b = W_comb + 32768 + 16384;

    k_dense<true><<<1024, 256, 0, stream>>>(X, h, W_in, b_in);         // h = relu(XW+b)
    k_dense<false><<<1024, 256, 0, stream>>>(h, hn, W0t, b_comb);      // hn = b + hWt
    k_msggemm<<<1024, 256, 0, stream>>>(h, hn, W0b, row_ptr, edge_src, inv_deg);
    k_dense<false><<<1024, 256, 0, stream>>>(hn, h, W1t, b_comb + 128);
    k_msggemm<<<1024, 256, 0, stream>>>(hn, h, W1b, row_ptr, edge_src, inv_deg);
    k_outv2<<<1024, 256, 0, stream>>>(h, W_out, b_out, out);
}

// Round 9
// 505.200 us; speedup vs baseline: 2.7618x; 1.2385x over previous
//
#include <hip/hip_runtime.h>

#define N_NODES 50000
#define N_EDGES 600000
#define NBLK 49  // ceil(50000/1024)

// ---------------- adj layout detection (int64 vs int32) ----------------
__global__ void k_detect(const int* __restrict__ adj_w, int* __restrict__ mode) {
    if (threadIdx.x == 0 && blockIdx.x == 0) {
        int allz = 1;
        for (int i = 1; i < 128; i += 2)
            if (adj_w[i] != 0) { allz = 0; break; }
        *mode = allz;  // 1 => int64 layout
    }
}
__device__ __forceinline__ int adj_to(const int* a, int m, int e) {
    return m ? a[4 * e + 2] : a[2 * e + 1];
}
__device__ __forceinline__ int adj_fro(const int* a, int m, int e) {
    return m ? a[4 * e] : a[2 * e];
}

// ---------------- CSR build ----------------
__global__ void k_count(const int* __restrict__ adj_w, const int* __restrict__ mode,
                        int* __restrict__ deg) {
    int e = blockIdx.x * blockDim.x + threadIdx.x;
    if (e < N_EDGES) atomicAdd(&deg[adj_to(adj_w, *mode, e)], 1);
}

// block-local exclusive scan; bsum[blk] = block total
__global__ void k_scan1(const int* __restrict__ deg, int* __restrict__ row_ptr,
                        int* __restrict__ bsum) {
    __shared__ int s[1024];
    int tid = threadIdx.x, i = blockIdx.x * 1024 + tid;
    int v = (i < N_NODES) ? deg[i] : 0;
    s[tid] = v;
    __syncthreads();
    for (int off = 1; off < 1024; off <<= 1) {
        int t = (tid >= off) ? s[tid - off] : 0;
        __syncthreads();
        s[tid] += t;
        __syncthreads();
    }
    if (i < N_NODES) row_ptr[i] = s[tid] - v;  // exclusive within block
    if (tid == 1023) bsum[blockIdx.x] = s[1023];
}

// exclusive scan of the 49 block sums (single tiny block)
__global__ void k_scan2(int* __restrict__ bsum) {
    __shared__ int s[64];
    int tid = threadIdx.x;
    int v = (tid < NBLK) ? bsum[tid] : 0;
    s[tid] = v;
    __syncthreads();
    for (int off = 1; off < 64; off <<= 1) {
        int t = (tid >= off) ? s[tid - off] : 0;
        __syncthreads();
        s[tid] += t;
        __syncthreads();
    }
    if (tid < NBLK) bsum[tid] = s[tid] - v;
}

// add block offsets; emit cursor, inv_deg, row_ptr[N]
__global__ void k_scan3(const int* __restrict__ deg, int* __restrict__ row_ptr,
                        const int* __restrict__ bsum, int* __restrict__ cursor,
                        float* __restrict__ inv_deg) {
    int i = blockIdx.x * 1024 + threadIdx.x;
    if (i < N_NODES) {
        int rp = row_ptr[i] + bsum[i >> 10];
        row_ptr[i] = rp;
        cursor[i] = rp;
        inv_deg[i] = 1.0f / fmaxf((float)deg[i], 1.0f);
    }
    if (i == 0) row_ptr[N_NODES] = N_EDGES;  // total is a constant
}

__global__ void k_fill(const int* __restrict__ adj_w, const int* __restrict__ mode,
                       int* __restrict__ cursor, int* __restrict__ edge_src) {
    int e = blockIdx.x * blockDim.x + threadIdx.x;
    if (e < N_EDGES) {
        int m = *mode;
        int to = adj_to(adj_w, m, e);
        int slot = atomicAdd(&cursor[to], 1);
        edge_src[slot] = adj_fro(adj_w, m, e);
    }
}

// ---- dense GEMM out[row] = [relu](bias + in[row] @ W), W (128x128) in registers ----
// launch_bounds(256,4): VGPR cap 128 so wr[64] is truly register-resident.
template <bool RELU>
__global__ __launch_bounds__(256, 4) void k_dense(const float* __restrict__ in,
                                                  float* __restrict__ outp,
                                                  const float* __restrict__ W,
                                                  const float* __restrict__ bias) {
    __shared__ __align__(16) float xs[8][128];
    const int t = threadIdx.x, w = t >> 6, l = t & 63;
    const int q = l >> 5, c = w * 32 + (l & 31);
    float wr[64];
#pragma unroll
    for (int j = 0; j < 64; j++) wr[j] = W[(64 * q + j) * 128 + c];
    const float b = bias[c];
    const int nch = N_NODES / 8;  // 6250
    for (int ch = blockIdx.x; ch < nch; ch += gridDim.x) {
        const int R0 = ch * 8;
        ((float4*)xs)[t] = ((const float4*)(in + (size_t)R0 * 128))[t];
        __syncthreads();
#pragma unroll
        for (int r = 0; r < 8; r++) {
            float a = 0.f;
#pragma unroll
            for (int jj = 0; jj < 16; jj++) {
                float4 x4 = *(const float4*)&xs[r][64 * q + jj * 4];
                a += x4.x * wr[jj * 4] + x4.y * wr[jj * 4 + 1] +
                     x4.z * wr[jj * 4 + 2] + x4.w * wr[jj * 4 + 3];
            }
            a += __shfl_xor(a, 32);
            if (l < 32) {
                float v = a + b;
                if (RELU) v = fmaxf(v, 0.f);
                outp[(size_t)(R0 + r) * 128 + c] = v;
            }
        }
        __syncthreads();
    }
}

// ---- fused gather + dense: hio[row] = relu(hio[row] + msg[row] @ W) ----
__global__ __launch_bounds__(256, 4) void k_msggemm(const float* __restrict__ hin,
                                                    float* __restrict__ hio,
                                                    const float* __restrict__ W,
                                                    const int* __restrict__ row_ptr,
                                                    const int* __restrict__ edge_src,
                                                    const float* __restrict__ inv_deg) {
    __shared__ __align__(16) float xs[8][128];
    const int t = threadIdx.x, w = t >> 6, l = t & 63;
    const int q = l >> 5, c = w * 32 + (l & 31);
    float wr[64];
#pragma unroll
    for (int j = 0; j < 64; j++) wr[j] = W[(64 * q + j) * 128 + c];
    const float2* h2 = (const float2*)hin;
    const int nch = N_NODES / 8;
    for (int ch = blockIdx.x; ch < nch; ch += gridDim.x) {
        const int R0 = ch * 8;
        for (int rr = 0; rr < 2; rr++) {
            const int row = R0 + 2 * w + rr;
            const int e0 = row_ptr[row], e1 = row_ptr[row + 1];
            float s0x = 0.f, s0y = 0.f, s1x = 0.f, s1y = 0.f;
            float s2x = 0.f, s2y = 0.f, s3x = 0.f, s3y = 0.f;
            int e = e0;
            for (; e + 3 < e1; e += 4) {  // 4-deep MLP
                const int i0 = edge_src[e], i1 = edge_src[e + 1];
                const int i2 = edge_src[e + 2], i3 = edge_src[e + 3];
                float2 v0 = h2[(size_t)i0 * 64 + l];
                float2 v1 = h2[(size_t)i1 * 64 + l];
                float2 v2 = h2[(size_t)i2 * 64 + l];
                float2 v3 = h2[(size_t)i3 * 64 + l];
                s0x += v0.x; s0y += v0.y; s1x += v1.x; s1y += v1.y;
                s2x += v2.x; s2y += v2.y; s3x += v3.x; s3y += v3.y;
            }
            for (; e < e1; e++) {
                float2 v = h2[(size_t)edge_src[e] * 64 + l];
                s0x += v.x; s0y += v.y;
            }
            const float inv = inv_deg[row];
            float2 m;
            m.x = (s0x + s1x + s2x + s3x) * inv;
            m.y = (s0y + s1y + s2y + s3y) * inv;
            *(float2*)&xs[2 * w + rr][2 * l] = m;
        }
        __syncthreads();
#pragma unroll
        for (int r = 0; r < 8; r++) {
            float a = 0.f;
#pragma unroll
            for (int jj = 0; jj < 16; jj++) {
                float4 x4 = *(const float4*)&xs[r][64 * q + jj * 4];
                a += x4.x * wr[jj * 4] + x4.y * wr[jj * 4 + 1] +
                     x4.z * wr[jj * 4 + 2] + x4.w * wr[jj * 4 + 3];
            }
            a += __shfl_xor(a, 32);
            if (l < 32) {
                const size_t o = (size_t)(R0 + r) * 128 + c;
                hio[o] = fmaxf(a + hio[o], 0.f);
            }
        }
        __syncthreads();
    }
}

// ---- out = h @ W_out + b_out (f32). c = w*16+(l&15) (pad 40->64), q = l>>4 ----
__global__ __launch_bounds__(256, 4) void k_outv2(const float* __restrict__ hin,
                                                  const float* __restrict__ W,
                                                  const float* __restrict__ bias,
                                                  float* __restrict__ outp) {
    __shared__ __align__(16) float xs[8][128];
    const int t = threadIdx.x, w = t >> 6, l = t & 63;
    const int q = l >> 4, c = w * 16 + (l & 15);
    float wr[32];
#pragma unroll
    for (int j = 0; j < 32; j++) wr[j] = (c < 40) ? W[(32 * q + j) * 40 + c] : 0.f;
    const float b = (c < 40) ? bias[c] : 0.f;
    const int nch = N_NODES / 8;
    for (int ch = blockIdx.x; ch < nch; ch += gridDim.x) {
        const int R0 = ch * 8;
        ((float4*)xs)[t] = ((const float4*)(hin + (size_t)R0 * 128))[t];
        __syncthreads();
#pragma unroll
        for (int r = 0; r < 8; r++) {
            float a = 0.f;
#pragma unroll
            for (int jj = 0; jj < 8; jj++) {
                float4 x4 = *(const float4*)&xs[r][32 * q + jj * 4];
                a += x4.x * wr[jj * 4] + x4.y * wr[jj * 4 + 1] +
                     x4.z * wr[jj * 4 + 2] + x4.w * wr[jj * 4 + 3];
            }
            a += __shfl_xor(a, 16);
            a += __shfl_xor(a, 32);
            if (l < 16 && c < 40) outp[(size_t)(R0 + r) * 40 + c] = a + b;
        }
        __syncthreads();
    }
}

extern "C" void kernel_launch(void* const* d_in, const int* in_sizes, int n_in,
                              void* d_out, int out_size, void* d_ws, size_t ws_size,
                              hipStream_t stream) {
    // size-keyed input resolution with positional fallback (dict order)
    int ix[8] = {0, 1, 2, 3, 4, 5, 6, 7};
    int tmp[8] = {-1, -1, -1, -1, -1, -1, -1, -1};
    for (int i = 0; i < n_in && i < 8; i++) {
        switch (in_sizes[i]) {
            case 6400000: tmp[0] = i; break;
            case 1200000: case 2400000: tmp[1] = i; break;
            case 16384:   tmp[2] = i; break;
            case 128:     tmp[3] = i; break;
            case 65536:   tmp[4] = i; break;
            case 256:     tmp[5] = i; break;
            case 5120:    tmp[6] = i; break;
            case 40:      tmp[7] = i; break;
        }
    }
    int found = 0;
    for (int j = 0; j < 8; j++) found += (tmp[j] >= 0);
    if (found == 8) for (int j = 0; j < 8; j++) ix[j] = tmp[j];

    const float* X      = (const float*)d_in[ix[0]];
    const int*   adj_w  = (const int*)d_in[ix[1]];
    const float* W_in   = (const float*)d_in[ix[2]];
    const float* b_in   = (const float*)d_in[ix[3]];
    const float* W_comb = (const float*)d_in[ix[4]];
    const float* b_comb = (const float*)d_in[ix[5]];
    const float* W_out  = (const float*)d_in[ix[6]];
    const float* b_out  = (const float*)d_in[ix[7]];
    float* out = (float*)d_out;

    // ws layout unchanged from the proven 54,400,016B footprint
    char* base = (char*)d_ws;
    int*   deg      = (int*)(base + 0);
    int*   row_ptr  = (int*)(base + 200000);
    int*   cursor   = (int*)(base + 400004);
    float* inv_deg  = (float*)(base + 600004);
    int*   mode     = (int*)(base + 800004);
    int*   edge_src = (int*)(base + 800008);
    float* h        = (float*)(base + 3200016);
    float* hn       = h + 6400000;
    int*   bsum     = (int*)h;  // aliases h[0..48]; h written only after CSR build

    hipMemsetAsync(deg, 0, N_NODES * sizeof(int), stream);
    k_detect<<<1, 64, 0, stream>>>(adj_w, mode);
    k_count<<<(N_EDGES + 255) / 256, 256, 0, stream>>>(adj_w, mode, deg);
    k_scan1<<<NBLK, 1024, 0, stream>>>(deg, row_ptr, bsum);
    k_scan2<<<1, 64, 0, stream>>>(bsum);
    k_scan3<<<NBLK, 1024, 0, stream>>>(deg, row_ptr, bsum, cursor, inv_deg);
    k_fill<<<(N_EDGES + 255) / 256, 256, 0, stream>>>(adj_w, mode, cursor, edge_src);

    const float* W0t = W_comb;                  // layer 0 rows 0..127  (h part)
    const float* W0b = W_comb + 16384;          // layer 0 rows 128..255 (msg part)
    const float* W1t = W_comb + 32768;          // layer 1
    const float* W1b = W_comb + 32768 + 16384;

    k_dense<true><<<3125, 256, 0, stream>>>(X, h, W_in, b_in);
    k_dense<false><<<3125, 256, 0, stream>>>(h, hn, W0t, b_comb);
    k_msggemm<<<3125, 256, 0, stream>>>(h, hn, W0b, row_ptr, edge_src, inv_deg);
    k_dense<false><<<3125, 256, 0, stream>>>(hn, h, W1t, b_comb + 128);
    k_msggemm<<<3125, 256, 0, stream>>>(hn, h, W1b, row_ptr, edge_src, inv_deg);
    k_outv2<<<3125, 256, 0, stream>>>(h, W_out, b_out, out);
}

// Round 10
// 441.298 us; speedup vs baseline: 3.1617x; 1.1448x over previous
//
#include <hip/hip_runtime.h>

#define N_NODES 50000
#define N_EDGES 600000
#define NBLK 49  // ceil(50000/1024)

// ---------------- adj layout detection (int64 vs int32) ----------------
__global__ void k_detect(const int* __restrict__ adj_w, int* __restrict__ mode) {
    if (threadIdx.x == 0 && blockIdx.x == 0) {
        int allz = 1;
        for (int i = 1; i < 128; i += 2)
            if (adj_w[i] != 0) { allz = 0; break; }
        *mode = allz;  // 1 => int64 layout
    }
}
__device__ __forceinline__ int adj_to(const int* a, int m, int e) {
    return m ? a[4 * e + 2] : a[2 * e + 1];
}
__device__ __forceinline__ int adj_fro(const int* a, int m, int e) {
    return m ? a[4 * e] : a[2 * e];
}

// ---------------- CSR build ----------------
__global__ void k_count(const int* __restrict__ adj_w, const int* __restrict__ mode,
                        int* __restrict__ deg) {
    int e = blockIdx.x * blockDim.x + threadIdx.x;
    if (e < N_EDGES) atomicAdd(&deg[adj_to(adj_w, *mode, e)], 1);
}

__global__ void k_scan1(const int* __restrict__ deg, int* __restrict__ row_ptr,
                        int* __restrict__ bsum) {
    __shared__ int s[1024];
    int tid = threadIdx.x, i = blockIdx.x * 1024 + tid;
    int v = (i < N_NODES) ? deg[i] : 0;
    s[tid] = v;
    __syncthreads();
    for (int off = 1; off < 1024; off <<= 1) {
        int t = (tid >= off) ? s[tid - off] : 0;
        __syncthreads();
        s[tid] += t;
        __syncthreads();
    }
    if (i < N_NODES) row_ptr[i] = s[tid] - v;
    if (tid == 1023) bsum[blockIdx.x] = s[1023];
}

__global__ void k_scan2(int* __restrict__ bsum) {
    __shared__ int s[64];
    int tid = threadIdx.x;
    int v = (tid < NBLK) ? bsum[tid] : 0;
    s[tid] = v;
    __syncthreads();
    for (int off = 1; off < 64; off <<= 1) {
        int t = (tid >= off) ? s[tid - off] : 0;
        __syncthreads();
        s[tid] += t;
        __syncthreads();
    }
    if (tid < NBLK) bsum[tid] = s[tid] - v;
}

__global__ void k_scan3(const int* __restrict__ deg, int* __restrict__ row_ptr,
                        const int* __restrict__ bsum, int* __restrict__ cursor,
                        float* __restrict__ inv_deg) {
    int i = blockIdx.x * 1024 + threadIdx.x;
    if (i < N_NODES) {
        int rp = row_ptr[i] + bsum[i >> 10];
        row_ptr[i] = rp;
        cursor[i] = rp;
        inv_deg[i] = 1.0f / fmaxf((float)deg[i], 1.0f);
    }
    if (i == 0) row_ptr[N_NODES] = N_EDGES;
}

__global__ void k_fill(const int* __restrict__ adj_w, const int* __restrict__ mode,
                       int* __restrict__ cursor, int* __restrict__ edge_src) {
    int e = blockIdx.x * blockDim.x + threadIdx.x;
    if (e < N_EDGES) {
        int m = *mode;
        int to = adj_to(adj_w, m, e);
        int slot = atomicAdd(&cursor[to], 1);
        edge_src[slot] = adj_fro(adj_w, m, e);
    }
}

// ---- dense GEMM out[row] = [relu](bias + in[row] @ W), W truly in registers ----
template <bool RELU>
__global__ __launch_bounds__(256, 4) void k_dense(const float* __restrict__ in,
                                                  float* __restrict__ outp,
                                                  const float* __restrict__ W,
                                                  const float* __restrict__ bias) {
    __shared__ __align__(16) float xs[8][128];
    const int t = threadIdx.x, w = t >> 6, l = t & 63;
    const int q = l >> 5, c = w * 32 + (l & 31);
    float wr[64];
#pragma unroll
    for (int j = 0; j < 64; j++) wr[j] = W[(64 * q + j) * 128 + c];
#pragma unroll
    for (int j = 0; j < 64; j++) asm volatile("" : "+v"(wr[j]));  // force VGPR residency
    const float b = bias[c];
    const int nch = N_NODES / 8;  // 6250
    for (int ch = blockIdx.x; ch < nch; ch += gridDim.x) {
        const int R0 = ch * 8;
        ((float4*)xs)[t] = ((const float4*)(in + (size_t)R0 * 128))[t];
        __syncthreads();
#pragma unroll
        for (int r = 0; r < 8; r++) {
            float a = 0.f;
#pragma unroll
            for (int jj = 0; jj < 16; jj++) {
                float4 x4 = *(const float4*)&xs[r][64 * q + jj * 4];
                a += x4.x * wr[jj * 4] + x4.y * wr[jj * 4 + 1] +
                     x4.z * wr[jj * 4 + 2] + x4.w * wr[jj * 4 + 3];
            }
            a += __shfl_xor(a, 32);
            if (l < 32) {
                float v = a + b;
                if (RELU) v = fmaxf(v, 0.f);
                outp[(size_t)(R0 + r) * 128 + c] = v;
            }
        }
        __syncthreads();
    }
}

// ---- fused gather + dense: hio[row] = relu(hio[row] + msg[row] @ W) ----
// Wave w handles rows (R0+2w, R0+2w+1): contiguous CSR edge range, MLP-8 batches.
__global__ __launch_bounds__(256, 4) void k_msggemm(const float* __restrict__ hin,
                                                    float* __restrict__ hio,
                                                    const float* __restrict__ W,
                                                    const int* __restrict__ row_ptr,
                                                    const int* __restrict__ edge_src,
                                                    const float* __restrict__ inv_deg) {
    __shared__ __align__(16) float xs[8][128];
    const int t = threadIdx.x, w = t >> 6, l = t & 63;
    const int q = l >> 5, c = w * 32 + (l & 31);
    float wr[64];
#pragma unroll
    for (int j = 0; j < 64; j++) wr[j] = W[(64 * q + j) * 128 + c];
#pragma unroll
    for (int j = 0; j < 64; j++) asm volatile("" : "+v"(wr[j]));  // force VGPR residency
    const float2* h2 = (const float2*)hin;
    const int nch = N_NODES / 8;
    for (int ch = blockIdx.x; ch < nch; ch += gridDim.x) {
        const int R0 = ch * 8;
        const int rowA = R0 + 2 * w;
        const int eA = row_ptr[rowA], eA1 = row_ptr[rowA + 1], eB1 = row_ptr[rowA + 2];
        float aAx = 0.f, aAy = 0.f, aBx = 0.f, aBy = 0.f;
        const int ecnt = eB1 - eA;
        for (int bse = 0; bse < ecnt; bse += 8) {
            float2 v[8];
#pragma unroll
            for (int i = 0; i < 8; i++) {
                int ee = eA + bse + i;
                int idx = (ee < eB1) ? ee : (eB1 - 1);  // clamp (safe: ecnt>0 here)
                v[i] = h2[(size_t)edge_src[idx] * 64 + l];
            }
#pragma unroll
            for (int i = 0; i < 8; i++) {
                int ee = eA + bse + i;
                if (ee < eA1) { aAx += v[i].x; aAy += v[i].y; }
                else if (ee < eB1) { aBx += v[i].x; aBy += v[i].y; }
            }
        }
        float2 mA, mB;
        const float invA = inv_deg[rowA], invB = inv_deg[rowA + 1];
        mA.x = aAx * invA; mA.y = aAy * invA;
        mB.x = aBx * invB; mB.y = aBy * invB;
        *(float2*)&xs[2 * w][2 * l] = mA;
        *(float2*)&xs[2 * w + 1][2 * l] = mB;
        __syncthreads();
#pragma unroll
        for (int r = 0; r < 8; r++) {
            float a = 0.f;
#pragma unroll
            for (int jj = 0; jj < 16; jj++) {
                float4 x4 = *(const float4*)&xs[r][64 * q + jj * 4];
                a += x4.x * wr[jj * 4] + x4.y * wr[jj * 4 + 1] +
                     x4.z * wr[jj * 4 + 2] + x4.w * wr[jj * 4 + 3];
            }
            a += __shfl_xor(a, 32);
            if (l < 32) {
                const size_t o = (size_t)(R0 + r) * 128 + c;
                hio[o] = fmaxf(a + hio[o], 0.f);
            }
        }
        __syncthreads();
    }
}

// ---- out = h @ W_out + b_out (f32). c = w*16+(l&15) (pad 40->64), q = l>>4 ----
__global__ __launch_bounds__(256, 4) void k_outv2(const float* __restrict__ hin,
                                                  const float* __restrict__ W,
                                                  const float* __restrict__ bias,
                                                  float* __restrict__ outp) {
    __shared__ __align__(16) float xs[8][128];
    const int t = threadIdx.x, w = t >> 6, l = t & 63;
    const int q = l >> 4, c = w * 16 + (l & 15);
    float wr[32];
#pragma unroll
    for (int j = 0; j < 32; j++) wr[j] = (c < 40) ? W[(32 * q + j) * 40 + c] : 0.f;
#pragma unroll
    for (int j = 0; j < 32; j++) asm volatile("" : "+v"(wr[j]));
    const float b = (c < 40) ? bias[c] : 0.f;
    const int nch = N_NODES / 8;
    for (int ch = blockIdx.x; ch < nch; ch += gridDim.x) {
        const int R0 = ch * 8;
        ((float4*)xs)[t] = ((const float4*)(hin + (size_t)R0 * 128))[t];
        __syncthreads();
#pragma unroll
        for (int r = 0; r < 8; r++) {
            float a = 0.f;
#pragma unroll
            for (int jj = 0; jj < 8; jj++) {
                float4 x4 = *(const float4*)&xs[r][32 * q + jj * 4];
                a += x4.x * wr[jj * 4] + x4.y * wr[jj * 4 + 1] +
                     x4.z * wr[jj * 4 + 2] + x4.w * wr[jj * 4 + 3];
            }
            a += __shfl_xor(a, 16);
            a += __shfl_xor(a, 32);
            if (l < 16 && c < 40) outp[(size_t)(R0 + r) * 40 + c] = a + b;
        }
        __syncthreads();
    }
}

extern "C" void kernel_launch(void* const* d_in, const int* in_sizes, int n_in,
                              void* d_out, int out_size, void* d_ws, size_t ws_size,
                              hipStream_t stream) {
    // size-keyed input resolution with positional fallback (dict order)
    int ix[8] = {0, 1, 2, 3, 4, 5, 6, 7};
    int tmp[8] = {-1, -1, -1, -1, -1, -1, -1, -1};
    for (int i = 0; i < n_in && i < 8; i++) {
        switch (in_sizes[i]) {
            case 6400000: tmp[0] = i; break;
            case 1200000: case 2400000: tmp[1] = i; break;
            case 16384:   tmp[2] = i; break;
            case 128:     tmp[3] = i; break;
            case 65536:   tmp[4] = i; break;
            case 256:     tmp[5] = i; break;
            case 5120:    tmp[6] = i; break;
            case 40:      tmp[7] = i; break;
        }
    }
    int found = 0;
    for (int j = 0; j < 8; j++) found += (tmp[j] >= 0);
    if (found == 8) for (int j = 0; j < 8; j++) ix[j] = tmp[j];

    const float* X      = (const float*)d_in[ix[0]];
    const int*   adj_w  = (const int*)d_in[ix[1]];
    const float* W_in   = (const float*)d_in[ix[2]];
    const float* b_in   = (const float*)d_in[ix[3]];
    const float* W_comb = (const float*)d_in[ix[4]];
    const float* b_comb = (const float*)d_in[ix[5]];
    const float* W_out  = (const float*)d_in[ix[6]];
    const float* b_out  = (const float*)d_in[ix[7]];
    float* out = (float*)d_out;

    // ws layout unchanged from the proven 54,400,016B footprint
    char* base = (char*)d_ws;
    int*   deg      = (int*)(base + 0);
    int*   row_ptr  = (int*)(base + 200000);
    int*   cursor   = (int*)(base + 400004);
    float* inv_deg  = (float*)(base + 600004);
    int*   mode     = (int*)(base + 800004);
    int*   edge_src = (int*)(base + 800008);
    float* h        = (float*)(base + 3200016);
    float* hn       = h + 6400000;
    int*   bsum     = (int*)h;  // aliases h[0..48]; h written only after CSR build

    hipMemsetAsync(deg, 0, N_NODES * sizeof(int), stream);
    k_detect<<<1, 64, 0, stream>>>(adj_w, mode);
    k_count<<<(N_EDGES + 255) / 256, 256, 0, stream>>>(adj_w, mode, deg);
    k_scan1<<<NBLK, 1024, 0, stream>>>(deg, row_ptr, bsum);
    k_scan2<<<1, 64, 0, stream>>>(bsum);
    k_scan3<<<NBLK, 1024, 0, stream>>>(deg, row_ptr, bsum, cursor, inv_deg);
    k_fill<<<(N_EDGES + 255) / 256, 256, 0, stream>>>(adj_w, mode, cursor, edge_src);

    const float* W0t = W_comb;                  // layer 0 rows 0..127  (h part)
    const float* W0b = W_comb + 16384;          // layer 0 rows 128..255 (msg part)
    const float* W1t = W_comb + 32768;          // layer 1
    const float* W1b = W_comb + 32768 + 16384;

    k_dense<true><<<3125, 256, 0, stream>>>(X, h, W_in, b_in);
    k_dense<false><<<3125, 256, 0, stream>>>(h, hn, W0t, b_comb);
    k_msggemm<<<6250, 256, 0, stream>>>(h, hn, W0b, row_ptr, edge_src, inv_deg);
    k_dense<false><<<3125, 256, 0, stream>>>(hn, h, W1t, b_comb + 128);
    k_msggemm<<<6250, 256, 0, stream>>>(hn, h, W1b, row_ptr, edge_src, inv_deg);
    k_outv2<<<3125, 256, 0, stream>>>(h, W_out, b_out, out);
}